// Round 3
// baseline (1275.965 us; speedup 1.0000x reference)
//
#include <hip/hip_runtime.h>

// Problem constants (fixed by setup_inputs)
constexpr int Bb = 16, Ll = 2048, Ee = 128, Hh = 256, Dd = 64, Kc = 512, Vv = 4096;
constexpr int NN = Bb * Ll;            // 32768 positions
constexpr int LOGITS = NN * Vv;        // 134217728

typedef __attribute__((ext_vector_type(8))) short bf16x8;   // 8 bf16 in 4 VGPRs
typedef __attribute__((ext_vector_type(4))) float f32x4;

// ---------------------------------------------------------------------------
// bf16 split helpers.
// bf16x3 (decoder, ~2^-16):  act [hi|lo|hi]  x  wt [hi|hi|lo]
// bf16x6 (encoder, ~2^-24):  A=A1+A2+A3 EXACT (24 mantissa bits = 3x8);
//   act [A1|A1|A2|A1|A2|A3]  x  wt [W1|W2|W1|W3|W2|W1]
//   = A1W1 + A1W2 + A2W1 + A1W3 + A2W2 + A3W1  (drops only ~2^-24 terms)
// MFMA multiplies bf16 pairs exactly (8x8<=24 bits) and accumulates fp32, so
// encoder z_e error is fp32-accumulation-rounding class -> codes exact.
__device__ __forceinline__ unsigned short f2bf_rne(float f) {
    unsigned int u = __float_as_uint(f);
    return (unsigned short)((u + 0x7fffu + ((u >> 16) & 1u)) >> 16);
}
__device__ __forceinline__ float bf2f(unsigned short h) {
    return __uint_as_float((unsigned int)h << 16);
}
__device__ __forceinline__ void split3f(float v, unsigned short& a1,
                                        unsigned short& a2, unsigned short& a3) {
    a1 = f2bf_rne(v);
    float r = v - bf2f(a1);      // exact (Sterbenz)
    a2 = f2bf_rne(r);
    r -= bf2f(a2);               // exact
    a3 = f2bf_rne(r);
}

// ---------------------------------------------------------------------------
// One-shot prep: all weight splits, the pre-split token-emb table (+guard
// row Vv), guard rows, padded e3 bias. Segment-dispatched by global id.
__global__ __launch_bounds__(256) void prep(
    const float* __restrict__ te,  const float* __restrict__ ew1,
    const float* __restrict__ ew2, const float* __restrict__ ew3,
    const float* __restrict__ eb3, const float* __restrict__ dw1,
    const float* __restrict__ dw2, const float* __restrict__ dw3,
    const float* __restrict__ outw, const float* __restrict__ cb,
    short* __restrict__ te6, short* __restrict__ we1, short* __restrict__ we2,
    short* __restrict__ we3, float* __restrict__ eb3p,
    short* __restrict__ wd1, short* __restrict__ wd2, short* __restrict__ wd3,
    short* __restrict__ wo3, short* __restrict__ cb3,
    short* __restrict__ h1_6, short* __restrict__ h1_3) {
    int id = blockIdx.x * 256 + threadIdx.x;
    unsigned short a1, a2, a3;
    // te6: (Vv+1) x 768, pattern [A1|A1|A2|A1|A2|A3], row Vv = zeros (guard)
    if (id < (Vv + 1) * Ee) {
        int t = id / Ee, c = id - t * Ee;
        size_t rb = (size_t)t * 768;
        if (t == Vv) {
            te6[rb + c] = 0; te6[rb + 128 + c] = 0; te6[rb + 256 + c] = 0;
            te6[rb + 384 + c] = 0; te6[rb + 512 + c] = 0; te6[rb + 640 + c] = 0;
            return;
        }
        split3f(te[(size_t)t * Ee + c], a1, a2, a3);
        te6[rb + c] = (short)a1;       te6[rb + 128 + c] = (short)a1;
        te6[rb + 256 + c] = (short)a2; te6[rb + 384 + c] = (short)a1;
        te6[rb + 512 + c] = (short)a2; te6[rb + 640 + c] = (short)a3;
        return;
    }
    id -= (Vv + 1) * Ee;
    // we1: ew1 (Hh,Ee,3) -> (Hh, 3 taps x [W1|W2|W1|W3|W2|W1]*128)
    if (id < Hh * Ee * 3) {
        int co = id / (Ee * 3); int rem = id - co * (Ee * 3);
        int ci = rem / 3, k = rem - ci * 3;
        split3f(ew1[id], a1, a2, a3);
        size_t b = (size_t)co * 2304 + (size_t)k * 768 + ci;
        we1[b] = (short)a1;       we1[b + 128] = (short)a2;
        we1[b + 256] = (short)a1; we1[b + 384] = (short)a3;
        we1[b + 512] = (short)a2; we1[b + 640] = (short)a1;
        return;
    }
    id -= Hh * Ee * 3;
    // we2: ew2 (Hh,Hh,3) -> (Hh, 3 x 1536)
    if (id < Hh * Hh * 3) {
        int co = id / (Hh * 3); int rem = id - co * (Hh * 3);
        int ci = rem / 3, k = rem - ci * 3;
        split3f(ew2[id], a1, a2, a3);
        size_t b = (size_t)co * 4608 + (size_t)k * 1536 + ci;
        we2[b] = (short)a1;        we2[b + 256] = (short)a2;
        we2[b + 512] = (short)a1;  we2[b + 768] = (short)a3;
        we2[b + 1024] = (short)a2; we2[b + 1280] = (short)a1;
        return;
    }
    id -= Hh * Hh * 3;
    // we3: ew3 (Dd,Hh) -> rows 0..63 of (128 x 1536)
    if (id < Dd * Hh) {
        int co = id / Hh, ci = id - co * Hh;
        split3f(ew3[id], a1, a2, a3);
        size_t b = (size_t)co * 1536 + ci;
        we3[b] = (short)a1;        we3[b + 256] = (short)a2;
        we3[b + 512] = (short)a1;  we3[b + 768] = (short)a3;
        we3[b + 1024] = (short)a2; we3[b + 1280] = (short)a1;
        return;
    }
    id -= Dd * Hh;
    // we3 zero rows 64..127 (padded outputs)
    if (id < 64 * 1536) { we3[(size_t)64 * 1536 + id] = 0; return; }
    id -= 64 * 1536;
    // wd1: dw1 (Hh,Dd) [hi|hi|lo]
    if (id < Hh * Dd) {
        int co = id / Dd, ci = id - co * Dd;
        float v = dw1[id];
        unsigned short hi = f2bf_rne(v), lo = f2bf_rne(v - bf2f(hi));
        size_t b = (size_t)co * 192 + ci;
        wd1[b] = (short)hi; wd1[b + 64] = (short)hi; wd1[b + 128] = (short)lo;
        return;
    }
    id -= Hh * Dd;
    // wd2: dw2 (Hh,Hh,3)
    if (id < Hh * Hh * 3) {
        int co = id / (Hh * 3); int rem = id - co * (Hh * 3);
        int ci = rem / 3, k = rem - ci * 3;
        float v = dw2[id];
        unsigned short hi = f2bf_rne(v), lo = f2bf_rne(v - bf2f(hi));
        size_t b = (size_t)co * 2304 + (size_t)k * 768 + ci;
        wd2[b] = (short)hi; wd2[b + 256] = (short)hi; wd2[b + 512] = (short)lo;
        return;
    }
    id -= Hh * Hh * 3;
    // wd3: dw3 (Ee,Hh)
    if (id < Ee * Hh) {
        int co = id / Hh, ci = id - co * Hh;
        float v = dw3[id];
        unsigned short hi = f2bf_rne(v), lo = f2bf_rne(v - bf2f(hi));
        size_t b = (size_t)co * 768 + ci;
        wd3[b] = (short)hi; wd3[b + 256] = (short)hi; wd3[b + 512] = (short)lo;
        return;
    }
    id -= Ee * Hh;
    // wo3: outw (Vv,Ee)
    if (id < Vv * Ee) {
        int co = id / Ee, ci = id - co * Ee;
        float v = outw[id];
        unsigned short hi = f2bf_rne(v), lo = f2bf_rne(v - bf2f(hi));
        size_t b = (size_t)co * 384 + ci;
        wo3[b] = (short)hi; wo3[b + 128] = (short)hi; wo3[b + 256] = (short)lo;
        return;
    }
    id -= Vv * Ee;
    // cb3: cb (Kc,Dd) activation pattern [hi|lo|hi]
    if (id < Kc * Dd) {
        int n = id / Dd, c = id - n * Dd;
        float v = cb[id];
        unsigned short hi = f2bf_rne(v), lo = f2bf_rne(v - bf2f(hi));
        size_t b = (size_t)n * 192 + c;
        cb3[b] = (short)hi; cb3[b + 64] = (short)lo; cb3[b + 128] = (short)hi;
        return;
    }
    id -= Kc * Dd;
    if (id < 1536) { h1_6[(size_t)NN * 1536 + id] = 0; return; }
    id -= 1536;
    if (id < 768)  { h1_3[(size_t)NN * 768 + id] = 0; return; }
    id -= 768;
    if (id < 128)  { eb3p[id] = (id < Dd) ? eb3[id] : 0.f; return; }
}
constexpr int PREP_TOTAL = (Vv + 1) * Ee + Hh * Ee * 3 + Hh * Hh * 3 + Dd * Hh
    + 64 * 1536 + Hh * Dd + Hh * Hh * 3 + Ee * Hh + Vv * Ee + Kc * Dd
    + 1536 + 768 + 128;

// ---------------------------------------------------------------------------
// Unified bf16 MFMA GEMM / conv1d: Y(M,Nout) = sum_taps A(M,KK)*B(Nout,KW*KK)^T.
// 128x128 tile, BK=32, 4 waves (2x2), 4x4 frags of 16x16x32 MFMA.
// LDS [kb(0..3)][row(0..127)][8 bf16]: free 2-way conflicts only; matches
// global_load_lds linear "base + lane*16" dest.
// GATHER: A row index comes from idx[] (per-lane global addr is allowed).
// OMODE: 0 = fp32 out (stride Nout), 1 = bf16x3 act out, 2 = bf16x6 act out.
__device__ __forceinline__ void gload16(const void* g, void* l) {
    __builtin_amdgcn_global_load_lds(
        (const __attribute__((address_space(1))) unsigned int*)g,
        (__attribute__((address_space(3))) unsigned int*)l, 16, 0, 0);
}

template <int KW, bool RELU, int OMODE, bool GATHER>
__global__ __launch_bounds__(256) void gemm_mfma(
    const short* __restrict__ A3, const int* __restrict__ idx, int guard,
    const short* __restrict__ B3, const float* __restrict__ bias,
    float* __restrict__ Yf, short* __restrict__ Y3, int KK, int Nout) {
    __shared__ short As[4096];   // 8 KB
    __shared__ short Bs[4096];

    const int tid  = threadIdx.x;
    const int lane = tid & 63;
    const int wid  = tid >> 6;

    // bijective XCD swizzle (all grids used are divisible by 8)
    const int nwg = gridDim.x;
    const int bid = blockIdx.x;
    const int swz = (bid & 7) * (nwg >> 3) + (bid >> 3);

    const int ntile = Nout >> 7;
    const int tm = swz / ntile;
    const int tn = swz - tm * ntile;
    const int m0 = tm << 7;
    const int n0 = tn << 7;

    const int wm = wid >> 1, wn = wid & 1;
    const int lr = lane & 15;
    const int kg = lane >> 4;

    f32x4 acc[4][4];
#pragma unroll
    for (int i = 0; i < 4; ++i)
#pragma unroll
        for (int j = 0; j < 4; ++j)
#pragma unroll
            for (int q = 0; q < 4; ++q) acc[i][j][q] = 0.f;

    const int BKW = KW * KK;   // B3 row length

    for (int kt = 0; kt < KW; ++kt) {
        const int shift = kt - (KW - 1) / 2;
        // per-tap A source rows (hoisted out of the K-loop)
        size_t arow[2];
#pragma unroll
        for (int j = 0; j < 2; ++j) {
            int n = m0 + j * 64 + lane;
            int src;
            if (KW > 1) {
                int sl = (n & (Ll - 1)) + shift;
                bool valid = (unsigned)sl < (unsigned)Ll;
                if (GATHER) src = valid ? idx[n + shift] : guard;
                else        src = valid ? n + shift : guard;
            } else {
                src = GATHER ? idx[n] : n;
            }
            arow[j] = (size_t)src * KK;
        }
        for (int k0 = 0; k0 < KK; k0 += 32) {
#pragma unroll
            for (int j = 0; j < 2; ++j)
                gload16(A3 + arow[j] + k0 + wid * 8,
                        As + (size_t)(wid * 128 + j * 64) * 8);
#pragma unroll
            for (int j = 0; j < 2; ++j)
                gload16(B3 + (size_t)(n0 + j * 64 + lane) * BKW + kt * KK + k0 + wid * 8,
                        Bs + (size_t)(wid * 128 + j * 64) * 8);
            __syncthreads();   // compiler drains vmcnt here

            bf16x8 af[4], bfr[4];
#pragma unroll
            for (int i = 0; i < 4; ++i)
                af[i] = *reinterpret_cast<const bf16x8*>(
                    &As[(size_t)(kg * 128 + wm * 64 + i * 16 + lr) * 8]);
#pragma unroll
            for (int j = 0; j < 4; ++j)
                bfr[j] = *reinterpret_cast<const bf16x8*>(
                    &Bs[(size_t)(kg * 128 + wn * 64 + j * 16 + lr) * 8]);
#pragma unroll
            for (int i = 0; i < 4; ++i)
#pragma unroll
                for (int j = 0; j < 4; ++j)
                    acc[i][j] = __builtin_amdgcn_mfma_f32_16x16x32_bf16(
                        af[i], bfr[j], acc[i][j], 0, 0, 0);
            __syncthreads();
        }
    }

    // ---- epilogue: C/D layout col=lane&15, row=(lane>>4)*4+reg ----
#pragma unroll
    for (int i = 0; i < 4; ++i) {
        int r0 = m0 + wm * 64 + i * 16 + kg * 4;
#pragma unroll
        for (int j = 0; j < 4; ++j) {
            int col = n0 + wn * 64 + j * 16 + lr;
            float bv = bias[col];
#pragma unroll
            for (int q = 0; q < 4; ++q) {
                float v = acc[i][j][q] + bv;
                if (RELU) v = fmaxf(v, 0.f);
                if (OMODE == 0) {
                    Yf[(size_t)(r0 + q) * Nout + col] = v;
                } else if (OMODE == 1) {
                    unsigned short hi = f2bf_rne(v), lo = f2bf_rne(v - bf2f(hi));
                    size_t rb = (size_t)(r0 + q) * (3 * Nout);
                    Y3[rb + col]            = (short)hi;
                    Y3[rb + Nout + col]     = (short)lo;
                    Y3[rb + 2 * Nout + col] = (short)hi;
                } else {
                    unsigned short s1, s2, s3;
                    split3f(v, s1, s2, s3);
                    size_t rb = (size_t)(r0 + q) * (6 * Nout);
                    Y3[rb + col]            = (short)s1;
                    Y3[rb + Nout + col]     = (short)s1;
                    Y3[rb + 2 * Nout + col] = (short)s2;
                    Y3[rb + 3 * Nout + col] = (short)s1;
                    Y3[rb + 4 * Nout + col] = (short)s2;
                    Y3[rb + 5 * Nout + col] = (short)s3;
                }
            }
        }
    }
}

// ---------------------------------------------------------------------------
// VQ argmin: per block, 64 rows vs all 512 codes (chunks of 64), D=64.
// z_e is stored padded to stride 128 (cols 0..63 real).
__global__ __launch_bounds__(256) void vq_kernel(
    const float* __restrict__ ze, const float* __restrict__ cb,
    int* __restrict__ codes_i, float* __restrict__ codes_f) {
    const int tid = threadIdx.x;
    const int tx = tid & 15, ty = tid >> 4;
    const int n0 = blockIdx.x * 64;

    __shared__ float Zs[Dd][64 + 4];   // [d][row]
    __shared__ float Cs[Dd][64 + 4];   // [d][code]
    __shared__ float bD[64][17];
    __shared__ int   bI[64][17];

#pragma unroll
    for (int v = 0; v < 4; ++v) {
        int f4 = v * 256 + tid;
        int row = f4 >> 4, d4 = f4 & 15;
        float4 z = *(const float4*)(ze + (size_t)(n0 + row) * 128 + d4 * 4);
        Zs[d4 * 4 + 0][row] = z.x;
        Zs[d4 * 4 + 1][row] = z.y;
        Zs[d4 * 4 + 2][row] = z.z;
        Zs[d4 * 4 + 3][row] = z.w;
    }

    float best[4];
    int   bidx[4];
#pragma unroll
    for (int i = 0; i < 4; i++) { best[i] = 3.4e38f; bidx[i] = 0; }

    for (int ch = 0; ch < Kc / 64; ++ch) {
        int c0 = ch * 64;
        __syncthreads();
#pragma unroll
        for (int v = 0; v < 4; ++v) {
            int f4 = v * 256 + tid;
            int j = f4 >> 4, d4 = f4 & 15;
            float4 w = *(const float4*)(cb + (size_t)(c0 + j) * Dd + d4 * 4);
            Cs[d4 * 4 + 0][j] = w.x;
            Cs[d4 * 4 + 1][j] = w.y;
            Cs[d4 * 4 + 2][j] = w.z;
            Cs[d4 * 4 + 3][j] = w.w;
        }
        __syncthreads();

        float dist[4][4];
#pragma unroll
        for (int i = 0; i < 4; i++)
#pragma unroll
            for (int j = 0; j < 4; j++) dist[i][j] = 0.f;

#pragma unroll 8
        for (int d = 0; d < Dd; ++d) {
            float a[4], b[4];
            *(float4*)a = *(const float4*)(&Zs[d][ty * 4]);
            *(float4*)b = *(const float4*)(&Cs[d][tx * 4]);
#pragma unroll
            for (int i = 0; i < 4; i++)
#pragma unroll
                for (int j = 0; j < 4; j++) {
                    float df = a[i] - b[j];
                    dist[i][j] = fmaf(df, df, dist[i][j]);
                }
        }
#pragma unroll
        for (int i = 0; i < 4; i++)
#pragma unroll
            for (int j = 0; j < 4; j++) {
                int ci = c0 + tx * 4 + j;
                if (dist[i][j] < best[i]) { best[i] = dist[i][j]; bidx[i] = ci; }
            }
    }
    __syncthreads();
#pragma unroll
    for (int i = 0; i < 4; i++) {
        bD[ty * 4 + i][tx] = best[i];
        bI[ty * 4 + i][tx] = bidx[i];
    }
    __syncthreads();
    if (tid < 64) {
        float bd = bD[tid][0];
        int   bi = bI[tid][0];
        for (int t = 1; t < 16; ++t) {
            float d = bD[tid][t];
            int   ix = bI[tid][t];
            if (d < bd || (d == bd && ix < bi)) { bd = d; bi = ix; }
        }
        codes_i[n0 + tid] = bi;
        codes_f[n0 + tid] = (float)bi;
    }
}

// ---------------------------------------------------------------------------
// Commitment loss with fused z_q gather, two-stage deterministic reduction.
__global__ __launch_bounds__(256) void commit_partial(
    const float* __restrict__ zep, const float* __restrict__ cb,
    const int* __restrict__ codes, float* __restrict__ partial) {
    float s = 0.f;
    for (int i4 = blockIdx.x * 256 + threadIdx.x; i4 < NN * 16; i4 += 1024 * 256) {
        int n = i4 >> 4, d4 = i4 & 15;
        float4 z = *(const float4*)(zep + (size_t)n * 128 + d4 * 4);
        float4 c = *(const float4*)(cb + (size_t)codes[n] * Dd + d4 * 4);
        float dx = z.x - c.x, dy = z.y - c.y, dz = z.z - c.z, dw = z.w - c.w;
        s = fmaf(dx, dx, s); s = fmaf(dy, dy, s);
        s = fmaf(dz, dz, s); s = fmaf(dw, dw, s);
    }
    for (int off = 32; off; off >>= 1) s += __shfl_down(s, off, 64);
    __shared__ float w[4];
    int lane = threadIdx.x & 63, wv = threadIdx.x >> 6;
    if (lane == 0) w[wv] = s;
    __syncthreads();
    if (threadIdx.x == 0) partial[blockIdx.x] = w[0] + w[1] + w[2] + w[3];
}

__global__ void commit_final(const float* __restrict__ partial, float* __restrict__ loss) {
    float s = 0.f;
    for (int i = threadIdx.x; i < 1024; i += 256) s += partial[i];
    for (int off = 32; off; off >>= 1) s += __shfl_down(s, off, 64);
    __shared__ float w[4];
    int lane = threadIdx.x & 63, wv = threadIdx.x >> 6;
    if (lane == 0) w[wv] = s;
    __syncthreads();
    if (threadIdx.x == 0)
        loss[0] = 0.1f * (w[0] + w[1] + w[2] + w[3]) / (float)(NN * Dd);
}

// ---------------------------------------------------------------------------
extern "C" void kernel_launch(void* const* d_in, const int* in_sizes, int n_in,
                              void* d_out, int out_size, void* d_ws, size_t ws_size,
                              hipStream_t stream) {
    const int*   x    = (const int*)d_in[0];
    const float* te   = (const float*)d_in[1];
    const float* ew1  = (const float*)d_in[2];
    const float* eb1  = (const float*)d_in[3];
    const float* ew2  = (const float*)d_in[4];
    const float* eb2  = (const float*)d_in[5];
    const float* ew3  = (const float*)d_in[6];
    const float* eb3  = (const float*)d_in[7];
    const float* cb   = (const float*)d_in[8];
    const float* dw1  = (const float*)d_in[9];
    const float* db1  = (const float*)d_in[10];
    const float* dw2  = (const float*)d_in[11];
    const float* db2  = (const float*)d_in[12];
    const float* dw3  = (const float*)d_in[13];
    const float* db3  = (const float*)d_in[14];
    const float* outw = (const float*)d_in[15];
    const float* outb = (const float*)d_in[16];

    char* ws = (char*)d_ws;
    size_t off = 0;
    auto alloc = [&](size_t bytes) -> void* {
        void* p = ws + off;
        off = (off + bytes + 255) & ~(size_t)255;
        return p;
    };
    // encoder bf16x6 path
    short* te6    = (short*)alloc((size_t)(Vv + 1) * 768 * 2);   // split emb table (+guard)
    short* we1_6  = (short*)alloc((size_t)Hh * 2304 * 2);
    short* we2_6  = (short*)alloc((size_t)Hh * 4608 * 2);
    short* we3_6  = (short*)alloc((size_t)128 * 1536 * 2);       // rows 64..127 zero
    float* eb3p   = (float*)alloc(128 * 4);
    short* h1_6   = (short*)alloc((size_t)(NN + 1) * 1536 * 2);  // +guard row
    short* h2_6   = (short*)alloc((size_t)(NN + 1) * 1536 * 2);
    float* zep    = (float*)alloc((size_t)NN * 128 * 4);         // z_e padded to 128
    // VQ / decoder bf16x3 path
    int*   codesi = (int*)alloc((size_t)NN * 4);
    float* part   = (float*)alloc(1024 * 4);
    short* cb3    = (short*)alloc((size_t)Kc * 192 * 2);
    short* h1_3   = (short*)alloc((size_t)(NN + 1) * 768 * 2);   // +guard row
    short* h2_3   = (short*)alloc((size_t)(NN + 1) * 768 * 2);
    short* h3_3   = (short*)alloc((size_t)(NN + 1) * 384 * 2);
    short* wd1_3  = (short*)alloc((size_t)Hh * 192 * 2);
    short* wd2_3  = (short*)alloc((size_t)Hh * 2304 * 2);
    short* wd3_3  = (short*)alloc((size_t)Ee * 768 * 2);
    short* wo3    = (short*)alloc((size_t)Vv * 384 * 2);

    float* out       = (float*)d_out;
    float* out_loss  = out + (size_t)LOGITS;
    float* out_codes = out_loss + 1;

    // 1) all weight/table prep in one kernel
    prep<<<dim3((PREP_TOTAL + 255) / 256), 256, 0, stream>>>(
        te, ew1, ew2, ew3, eb3, dw1, dw2, dw3, outw, cb,
        te6, we1_6, we2_6, we3_6, eb3p, wd1_3, wd2_3, wd3_3, wo3, cb3,
        h1_6, h1_3);

    // 2) Encoder: bf16x6 MFMA (fp32-exact class => codes exact)
    //    e1 gathers pre-split emb rows by token (guard token = Vv)
    gemm_mfma<3, true, 2, true><<<dim3(512), 256, 0, stream>>>(
        te6, x, Vv, we1_6, eb1, nullptr, h1_6, 768, Hh);
    gemm_mfma<3, true, 2, false><<<dim3(512), 256, 0, stream>>>(
        h1_6, nullptr, NN, we2_6, eb2, nullptr, h2_6, 1536, Hh);
    gemm_mfma<1, false, 0, false><<<dim3(256), 256, 0, stream>>>(
        h2_6, nullptr, 0, we3_6, eb3p, zep, nullptr, 1536, 128);

    // 3) VQ (+ fused-gather commitment loss)
    vq_kernel<<<dim3(NN / 64), 256, 0, stream>>>(zep, cb, codesi, out_codes);
    commit_partial<<<dim3(1024), 256, 0, stream>>>(zep, cb, codesi, part);
    commit_final<<<dim3(1), 256, 0, stream>>>(part, out_loss);

    // 4) Decoder: bf16x3 MFMA; d1 gathers codebook rows by code
    gemm_mfma<1, true, 1, true><<<dim3(512), 256, 0, stream>>>(
        cb3, codesi, 0, wd1_3, db1, nullptr, h1_3, 192, Hh);
    gemm_mfma<3, true, 1, false><<<dim3(512), 256, 0, stream>>>(
        h1_3, nullptr, NN, wd2_3, db2, nullptr, h2_3, 768, Hh);
    gemm_mfma<1, true, 1, false><<<dim3(256), 256, 0, stream>>>(
        h2_3, nullptr, 0, wd3_3, db3, nullptr, h3_3, 768, Ee);

    // 5) Vocab projection -> logits (bf16x3, fp32 out)
    gemm_mfma<1, false, 0, false><<<dim3(8192), 256, 0, stream>>>(
        h3_3, nullptr, 0, wo3, outb, out, nullptr, 384, Vv);
}